// Round 11
// baseline (226.078 us; speedup 1.0000x reference)
//
#include <hip/hip_runtime.h>

// (B,N,D,K) = (32, 2048, 512, 256)
#define CB 32
#define CN 2048
#define CD 512
#define CK 256

typedef __bf16 bf16x8 __attribute__((ext_vector_type(8)));
typedef float  f32x4  __attribute__((ext_vector_type(4)));

__device__ __forceinline__ unsigned pk2bf(float a, float b) {   // RNE pack: 2 f32 -> bf16x2
    union { float f; unsigned u; } x, y; x.f = a; y.f = b;
    unsigned ru = x.u + 0x7fffu + ((x.u >> 16) & 1u);
    unsigned rv = y.u + 0x7fffu + ((y.u >> 16) & 1u);
    return (ru >> 16) | (rv & 0xffff0000u);
}

__device__ __forceinline__ unsigned short bf16r(float a) {      // RNE f32 -> bf16
    union { float f; unsigned u; } x; x.f = a;
    unsigned r = x.u + 0x7fffu + ((x.u >> 16) & 1u);
    return (unsigned short)(r >> 16);
}

__device__ __forceinline__ void glds16(const void* g, void* l) {
    __builtin_amdgcn_global_load_lds(
        (const __attribute__((address_space(1))) void*)g,
        (__attribute__((address_space(3))) void*)l, 16, 0, 0);
}

// ---------------- K0: prep = {WiT transpose tiles: blocks 0..31} ∪
//                          {vQp partial GEMV: blocks 32..287} ----------------
__global__ __launch_bounds__(256) void prep_kernel(
        const float* __restrict__ Wi, const float* __restrict__ Wq,
        const float* __restrict__ vQ, const float* __restrict__ bq,
        unsigned short* __restrict__ WiT, float* __restrict__ vQpP)
{
    const int tid = threadIdx.x;
    if (blockIdx.x < 32) {
        // 64x64 tile transpose Wi[d][k] -> WiT[k][d] (bf16), coalesced both sides
        const int t = blockIdx.x;
        const int d0 = (t >> 2) * 64, k0 = (t & 3) * 64;
        __shared__ float sT[64][68];                 // pad 68: 16B-aligned rows
        const int r = tid >> 4, c4 = (tid & 15) * 4;
        #pragma unroll
        for (int i = 0; i < 4; ++i) {
            float4 v = *reinterpret_cast<const float4*>(
                Wi + (size_t)(d0 + r + i * 16) * CK + k0 + c4);
            *reinterpret_cast<float4*>(&sT[r + i * 16][c4]) = v;
        }
        __syncthreads();
        const int k = tid >> 2, dg = (tid & 3) * 16;
        unsigned short __attribute__((aligned(16))) ov[16];
        #pragma unroll
        for (int j = 0; j < 16; ++j) ov[j] = bf16r(sT[dg + j][k]);
        unsigned short* dst = WiT + (size_t)(k0 + k) * CD + d0 + dg;
        *reinterpret_cast<uint4*>(dst)     = *reinterpret_cast<const uint4*>(&ov[0]);
        *reinterpret_cast<uint4*>(dst + 8) = *reinterpret_cast<const uint4*>(&ov[8]);
    } else {
        // vQpP[b][j][k] = sum_{d in 64-slice j} vQ[b][d]*Wq[d][k]  (+bq at j==0)
        const int bb = blockIdx.x - 32;
        const int b = bb >> 3, j = bb & 7;
        __shared__ float sq[64];
        if (tid < 64) sq[tid] = vQ[b * CD + j * 64 + tid];
        __syncthreads();
        float acc = (j == 0) ? bq[tid] : 0.f;
        const float* wq = Wq + (size_t)j * 64 * CK + tid;
        #pragma unroll
        for (int d = 0; d < 64; d += 8) {
            float wv[8];
            #pragma unroll
            for (int u = 0; u < 8; ++u) wv[u] = wq[(d + u) * CK];   // 8 loads in flight
            #pragma unroll
            for (int u = 0; u < 8; ++u) acc += sq[d + u] * wv[u];
        }
        vQpP[(size_t)bb * CK + tid] = acc;
    }
}

// ---------------- K1: fused scores + softmax pieces + K-space num ----------------
// Round-7 BARRIER-FREE structure (d-split phase-resident B) with the round-8
// SPILL FIX (named A registers, compile-time unrolled P/Q alternation):
//   BM=256 rows/block, 512 threads (8 waves x 32 rows), grid (8,32) = 256 blocks
//   = exactly 1 block/CU (128 KB LDS). Phase p in {0,1}: WiT[256k][256d-chunk]
//   resident in LDS (XOR-swizzled, staged via inverse-swizzled glds sources).
//   Within a phase: 4 d-steps, ZERO barriers — waves free-run, A global->reg
//   ping-pong 1 step ahead. 3 sync events per block total.
__global__ __launch_bounds__(512, 2) void scores_fused_kernel(
        const float* __restrict__ vI, const unsigned short* __restrict__ WiT,
        const float* __restrict__ vQpP, const float* __restrict__ Wp,
        float* __restrict__ numP, float* __restrict__ Zp, float* __restrict__ mP)
{
    constexpr int BM = 256;
    __shared__ __align__(16) unsigned short sBh[CK * 256];   // [256 k][256 d] bf16 = 128 KB
    float* fb   = (float*)sBh;        // aliased AFTER the K-loop only
    float* svq  = fb;                 // [256] combined vQp
    float* swp  = fb + 256;           // [256] Wp
    float* sS   = fb + 512;           // [256] row scores
    float* sW   = fb + 768;           // [256] exp weights
    float* sZ   = fb + 1024;          // [8]
    float* snum = fb + 1040;          // [8][256] num wave-partials

    const int tid  = threadIdx.x;
    const int b    = blockIdx.y;
    const int n0   = blockIdx.x * BM;
    const int wave = tid >> 6;        // 0..7
    const int lane = tid & 63;
    const int col  = lane & 15;
    const int quad = lane >> 4;

    const float* vIb   = vI + ((size_t)b * CN + n0) * CD;
    const float* aBase = vIb + (size_t)(wave * 32 + col) * CD + quad * 8;

    f32x4 acc[2][16];
    #pragma unroll
    for (int mt = 0; mt < 2; ++mt)
        #pragma unroll
        for (int kt = 0; kt < 16; ++kt)
            acc[mt][kt] = (f32x4){0.f, 0.f, 0.f, 0.f};

// ---- named A register sets (NO arrays, NO runtime selection) ----
#define DECL_A(S) f32x4 a##S##0, a##S##1, a##S##2, a##S##3, \
                        a##S##4, a##S##5, a##S##6, a##S##7;
    DECL_A(P)
    DECL_A(Q)

#define LOADA(S, D0) do {                                                     \
    const float* p0_ = aBase + (D0);                                          \
    const float* p1_ = aBase + 16 * CD + (D0);                                \
    a##S##0 = *reinterpret_cast<const f32x4*>(p0_);                           \
    a##S##1 = *reinterpret_cast<const f32x4*>(p0_ + 4);                       \
    a##S##2 = *reinterpret_cast<const f32x4*>(p0_ + 32);                      \
    a##S##3 = *reinterpret_cast<const f32x4*>(p0_ + 36);                      \
    a##S##4 = *reinterpret_cast<const f32x4*>(p1_);                           \
    a##S##5 = *reinterpret_cast<const f32x4*>(p1_ + 4);                       \
    a##S##6 = *reinterpret_cast<const f32x4*>(p1_ + 32);                      \
    a##S##7 = *reinterpret_cast<const f32x4*>(p1_ + 36);                      \
} while (0)

// Stage phase-p B-chunk: LDS row k (512 B) = WiT[k][256p + dl] with byte swizzle
// dlb -> dlb ^ ((k&7)<<4); glds writes linearly so the SOURCE carries the
// inverse swizzle (both-sides rule). 2 k-rows per instr, 16 instr/wave.
#define STAGEB(P_) do {                                                       \
    _Pragma("unroll")                                                         \
    for (int i_ = 0; i_ < 16; ++i_) {                                         \
        const int k0_  = wave * 32 + i_ * 2;                                  \
        const int k_   = k0_ + (lane >> 5);                                   \
        const int dlb_ = ((lane & 31) * 16) ^ ((k_ & 7) << 4);                \
        glds16(WiT + (size_t)k_ * CD + (P_) * 256 + (dlb_ >> 1),              \
               (unsigned short*)sBh + k0_ * 256);                             \
    }                                                                         \
} while (0)

#define PACK2(lo, hi) ({                                                      \
    union { unsigned u[4]; bf16x8 v; } t_;                                    \
    t_.u[0] = pk2bf((lo).x, (lo).y); t_.u[1] = pk2bf((lo).z, (lo).w);         \
    t_.u[2] = pk2bf((hi).x, (hi).y); t_.u[3] = pk2bf((hi).z, (hi).w);         \
    t_.v; })

// compute one d-step (phase-local TL in 0..3) against resident swizzled B
#define COMPUTE(S, TL) do {                                                   \
    bf16x8 f00_ = PACK2(a##S##0, a##S##1);   /* mt0, s0 */                    \
    bf16x8 f01_ = PACK2(a##S##2, a##S##3);   /* mt0, s1 */                    \
    bf16x8 f10_ = PACK2(a##S##4, a##S##5);   /* mt1, s0 */                    \
    bf16x8 f11_ = PACK2(a##S##6, a##S##7);   /* mt1, s1 */                    \
    _Pragma("unroll")                                                         \
    for (int s_ = 0; s_ < 2; ++s_) {                                          \
        const int slot_ = ((s_ * 4 + quad) ^ (col & 7)) << 4;                 \
        const unsigned short* base_ =                                         \
            sBh + col * 256 + (((TL) * 128 + slot_) >> 1);                    \
        const bf16x8 am0_ = s_ ? f01_ : f00_;                                 \
        const bf16x8 am1_ = s_ ? f11_ : f10_;                                 \
        _Pragma("unroll")                                                     \
        for (int kc_ = 0; kc_ < 4; ++kc_) {                                   \
            const unsigned short* kb_ = base_ + (size_t)(kc_ * 4) * 16 * 256; \
            bf16x8 b0_ = *reinterpret_cast<const bf16x8*>(kb_);               \
            bf16x8 b1_ = *reinterpret_cast<const bf16x8*>(kb_ + 16 * 256);    \
            bf16x8 b2_ = *reinterpret_cast<const bf16x8*>(kb_ + 32 * 256);    \
            bf16x8 b3_ = *reinterpret_cast<const bf16x8*>(kb_ + 48 * 256);    \
            acc[0][kc_ * 4 + 0] = __builtin_amdgcn_mfma_f32_16x16x32_bf16(    \
                am0_, b0_, acc[0][kc_ * 4 + 0], 0, 0, 0);                     \
            acc[1][kc_ * 4 + 0] = __builtin_amdgcn_mfma_f32_16x16x32_bf16(    \
                am1_, b0_, acc[1][kc_ * 4 + 0], 0, 0, 0);                     \
            acc[0][kc_ * 4 + 1] = __builtin_amdgcn_mfma_f32_16x16x32_bf16(    \
                am0_, b1_, acc[0][kc_ * 4 + 1], 0, 0, 0);                     \
            acc[1][kc_ * 4 + 1] = __builtin_amdgcn_mfma_f32_16x16x32_bf16(    \
                am1_, b1_, acc[1][kc_ * 4 + 1], 0, 0, 0);                     \
            acc[0][kc_ * 4 + 2] = __builtin_amdgcn_mfma_f32_16x16x32_bf16(    \
                am0_, b2_, acc[0][kc_ * 4 + 2], 0, 0, 0);                     \
            acc[1][kc_ * 4 + 2] = __builtin_amdgcn_mfma_f32_16x16x32_bf16(    \
                am1_, b2_, acc[1][kc_ * 4 + 2], 0, 0, 0);                     \
            acc[0][kc_ * 4 + 3] = __builtin_amdgcn_mfma_f32_16x16x32_bf16(    \
                am0_, b3_, acc[0][kc_ * 4 + 3], 0, 0, 0);                     \
            acc[1][kc_ * 4 + 3] = __builtin_amdgcn_mfma_f32_16x16x32_bf16(    \
                am1_, b3_, acc[1][kc_ * 4 + 3], 0, 0, 0);                     \
        }                                                                     \
    }                                                                         \
} while (0)

    // prologue: A(0) + B-phase0 in flight
    LOADA(P, 0);
    STAGEB(0);
    __syncthreads();

    // ---- phase 0: d in [0,256), 4 steps, NO barriers ----
    LOADA(Q,  64); COMPUTE(P, 0);
    LOADA(P, 128); COMPUTE(Q, 1);
    LOADA(Q, 192); COMPUTE(P, 2);
    LOADA(P, 256); COMPUTE(Q, 3);   // prefetches phase-1's first chunk

    // ---- mid: restage B for phase 1 ----
    __syncthreads();                 // all phase-0 B reads done
    STAGEB(1);
    asm volatile("s_waitcnt vmcnt(0)" ::: "memory");
    __builtin_amdgcn_s_barrier();

    // ---- phase 1: d in [256,512), 4 steps, NO barriers ----
    LOADA(Q, 320); COMPUTE(P, 0);
    LOADA(P, 384); COMPUTE(Q, 1);
    LOADA(Q, 448); COMPUTE(P, 2);
    COMPUTE(Q, 3);
    __syncthreads();   // all B reads done; safe to alias LDS

    // ---- epilogue 0: combine vQp partials + Wp into LDS ----
    if (tid < CK) {
        float a = 0.f;
        #pragma unroll
        for (int j = 0; j < 8; ++j) a += vQpP[(b * 8 + j) * CK + tid];
        svq[tid] = a;
        swp[tid] = Wp[tid];
    }
    __syncthreads();

    // ---- epilogue 1: per-row scores (each wave owns ALL k for its rows) ----
    float vq[16], wp[16];
    #pragma unroll
    for (int kt = 0; kt < 16; ++kt) {
        vq[kt] = svq[kt * 16 + col];
        wp[kt] = swp[kt * 16 + col];
    }
    float sp[2][4];
    #pragma unroll
    for (int mt = 0; mt < 2; ++mt)
        #pragma unroll
        for (int r = 0; r < 4; ++r) {
            float s = 0.f;
            #pragma unroll
            for (int kt = 0; kt < 16; ++kt) {
                float v = acc[mt][kt][r] + vq[kt];
                v = v > 0.f ? v : 0.01f * v;
                s += v * wp[kt];
            }
            sp[mt][r] = s;
        }
    #pragma unroll
    for (int off = 1; off < 16; off <<= 1)
        #pragma unroll
        for (int mt = 0; mt < 2; ++mt)
            #pragma unroll
            for (int r = 0; r < 4; ++r)
                sp[mt][r] += __shfl_xor(sp[mt][r], off);
    if (col == 0) {
        #pragma unroll
        for (int mt = 0; mt < 2; ++mt)
            #pragma unroll
            for (int r = 0; r < 4; ++r)
                sS[wave * 32 + mt * 16 + quad * 4 + r] = sp[mt][r];
    }
    __syncthreads();

    // ---- epilogue 2: block-local softmax pieces (256 rows) ----
    float m = -1e30f;
    #pragma unroll 8
    for (int i = 0; i < BM; ++i) m = fmaxf(m, sS[i]);
    if (tid < BM) sW[tid] = __expf(sS[tid] - m);
    __syncthreads();
    float z = (tid < BM) ? sW[tid] : 0.f;
    #pragma unroll
    for (int off = 32; off > 0; off >>= 1) z += __shfl_xor(z, off);
    if (lane == 0 && wave < 4) sZ[wave] = z;
    __syncthreads();
    const int pidx = b * 8 + blockIdx.x;
    if (tid == 0) {
        Zp[pidx] = sZ[0] + sZ[1] + sZ[2] + sZ[3];
        mP[pidx] = m;
    }

    // ---- epilogue 3: K-space num from acc registers (vI never re-read) ----
    float w8[2][4];
    #pragma unroll
    for (int mt = 0; mt < 2; ++mt)
        #pragma unroll
        for (int r = 0; r < 4; ++r)
            w8[mt][r] = sW[wave * 32 + mt * 16 + quad * 4 + r];
    float nk[16];
    #pragma unroll
    for (int kt = 0; kt < 16; ++kt) {
        float s = 0.f;
        #pragma unroll
        for (int mt = 0; mt < 2; ++mt)
            #pragma unroll
            for (int r = 0; r < 4; ++r)
                s += w8[mt][r] * acc[mt][kt][r];
        s += __shfl_xor(s, 16);      // reduce across quads (rows)
        s += __shfl_xor(s, 32);
        nk[kt] = s;
    }
    if (quad == 0) {
        #pragma unroll
        for (int kt = 0; kt < 16; ++kt)
            snum[wave * 256 + kt * 16 + col] = nk[kt];
    }
    __syncthreads();
    if (tid < CK) {
        float s = 0.f;
        #pragma unroll
        for (int w = 0; w < 8; ++w) s += snum[w * 256 + tid];
        numP[(size_t)pidx * CK + tid] = s;
    }
}

// ---------------- K2: combine partials -> out = num/Z + vQp (elementwise) ----------------
__global__ __launch_bounds__(256) void finalize_kernel(
        const float* __restrict__ numP, const float* __restrict__ Zp,
        const float* __restrict__ mP, const float* __restrict__ vQpP,
        float* __restrict__ out)
{
    const int b = blockIdx.x, tid = threadIdx.x;
    float M = -1e30f;
    #pragma unroll
    for (int j = 0; j < 8; ++j) M = fmaxf(M, mP[b * 8 + j]);
    float w[8]; float Zt = 0.f;
    #pragma unroll
    for (int j = 0; j < 8; ++j) {
        w[j] = __expf(mP[b * 8 + j] - M);
        Zt += w[j] * Zp[b * 8 + j];
    }
    const float inv = 1.f / Zt;
    float s = 0.f;
    #pragma unroll
    for (int j = 0; j < 8; ++j) s += w[j] * numP[(size_t)(b * 8 + j) * CK + tid];
    float vq = 0.f;
    #pragma unroll
    for (int j = 0; j < 8; ++j) vq += vQpP[(size_t)(b * 8 + j) * CK + tid];
    out[b * CK + tid] = s * inv + vq;
}

extern "C" void kernel_launch(void* const* d_in, const int* in_sizes, int n_in,
                              void* d_out, int out_size, void* d_ws, size_t ws_size,
                              hipStream_t stream)
{
    const float* vI = (const float*)d_in[0];   // [B,N,D]
    const float* vQ = (const float*)d_in[1];   // [B,D]
    const float* Wi = (const float*)d_in[2];   // [D,K]
    const float* Wq = (const float*)d_in[3];   // [D,K]
    const float* bq = (const float*)d_in[4];   // [K]
    const float* Wp = (const float*)d_in[5];   // [K,1]
    // d_in[6] = bp: softmax-invariant, unused
    float* out = (float*)d_out;                // [B,K]

    char* ws = (char*)d_ws;
    float*          vQpP = (float*)(ws);                   // 256 KB  [32*8][256]
    unsigned short* WiT  = (unsigned short*)(ws + 262144); // 256 KB  [256][512]
    float*          numP = (float*)(ws + 524288);          // 256 KB  [32*8][256]
    float*          Zp   = (float*)(ws + 786432);          //   1 KB
    float*          mP   = (float*)(ws + 787456);          //   1 KB

    prep_kernel        <<<288, 256, 0, stream>>>(Wi, Wq, vQ, bq, WiT, vQpP);
    scores_fused_kernel<<<dim3(CN / 256, CB), 512, 0, stream>>>(vI, WiT, vQpP, Wp,
                                                                numP, Zp, mP);
    finalize_kernel    <<<CB, 256, 0, stream>>>(numP, Zp, mP, vQpP, out);
}